// Round 9
// baseline (72.423 us; speedup 1.0000x reference)
//
#include <hip/hip_runtime.h>

// LocalL1Loss: out = mean_{n,h,w} min_{7x7 shift} mean_c |in - shifted(tgt, zero-pad)|
// inputs/targets: (16, 3, 512, 512) fp32. Output: scalar fp32.
// R8: 2 output rows/thread (rows 2ty, 2ty+1), 64x64 tile. Their di-windows
// share 6/7 target rows -> 8 row-loads serve 14 row-evals. Rolled u-loop
// (4 iters, two named buffers, prefetch next row before evals) to pipeline
// ds_read latency under evals and shrink code. f16 packed eval as R4.

constexpr int N = 16, C = 3, H = 512, W = 512;
constexpr int K = 7, HALO = 3;
constexpr int TH = 64, TW = 64;          // output tile per block
constexpr int SM_ROWS = TH + 2 * HALO;   // 70
constexpr int SM_D = 36;                 // dwords/row: halves [w0-4 .. w0+67]
constexpr int BLK = 256;                 // 32 ty x 8 tx, 2 rows per thread

typedef _Float16 h2 __attribute__((ext_vector_type(2)));
__device__ inline h2 u2h(unsigned u) { return __builtin_bit_cast(h2, u); }
__device__ inline h2 habs2(h2 x) {
    unsigned u = __builtin_bit_cast(unsigned, x) & 0x7fff7fffu;
    return __builtin_bit_cast(h2, u);
}

__device__ __forceinline__ void load_rows(const unsigned* p, unsigned t[3][8]) {
    #pragma unroll
    for (int c = 0; c < 3; ++c) {
        const uint4* q = reinterpret_cast<const uint4*>(p + c * (SM_ROWS * SM_D));
        uint4 lo = q[0], hi = q[1];
        t[c][0] = lo.x; t[c][1] = lo.y; t[c][2] = lo.z; t[c][3] = lo.w;
        t[c][4] = hi.x; t[c][5] = hi.y; t[c][6] = hi.z; t[c][7] = hi.w;
    }
}

__device__ __forceinline__ void align_row(const unsigned t[3][8], unsigned s[3][7]) {
    #pragma unroll
    for (int c = 0; c < 3; ++c)
        #pragma unroll
        for (int m = 0; m < 7; ++m)
            s[c][m] = __builtin_amdgcn_alignbit(t[c][m + 1], t[c][m], 16);
}

// one target row vs one output row: 7 dj x 4 pairs, even/odd-dj split accums
__device__ __forceinline__ void eval_row(const h2 ipk[3][4],
                                         const unsigned t[3][8],
                                         const unsigned s[3][7],
                                         h2* bE, h2* bO) {
    #pragma unroll
    for (int dj = 0; dj < K; ++dj) {
        #pragma unroll
        for (int p = 0; p < 4; ++p) {
            h2 w0h, w1h, w2h;
            if (dj & 1) {
                const int m = p + (dj + 1) / 2;
                w0h = u2h(t[0][m]); w1h = u2h(t[1][m]); w2h = u2h(t[2][m]);
            } else {
                const int m = p + dj / 2;
                w0h = u2h(s[0][m]); w1h = u2h(s[1][m]); w2h = u2h(s[2][m]);
            }
            h2 a0 = habs2(ipk[0][p] - w0h);
            h2 a1 = habs2(ipk[1][p] - w1h);
            h2 a2 = habs2(ipk[2][p] - w2h);
            h2 d  = a0 + a1 + a2;
            if (dj & 1) bO[p] = __builtin_elementwise_min(bO[p], d);
            else        bE[p] = __builtin_elementwise_min(bE[p], d);
        }
    }
}

__global__ __launch_bounds__(BLK, 4)
void local_l1_kernel(const float* __restrict__ inputs,
                     const float* __restrict__ targets,
                     float* __restrict__ out) {
    __shared__ unsigned sm_u[C * SM_ROWS * SM_D];   // 7560 dw = 30,240 B

    const int tid = threadIdx.x;
    const int w0 = blockIdx.x * TW;
    const int h0 = blockIdx.y * TH;
    const int n  = blockIdx.z;

    const int tx = tid & 7;    // strip index (w)
    const int ty = tid >> 3;   // 0..31; output rows 2ty, 2ty+1

    // ---- issue input loads first (2 rows x 3 ch x 2 float4) ----
    const float* ibase = inputs + ((size_t)n * C * H + (size_t)(h0 + 2 * ty)) * W
                       + (w0 + tx * 8);
    float4 ia[2][3], ib[2][3];
    #pragma unroll
    for (int r = 0; r < 2; ++r)
        #pragma unroll
        for (int c = 0; c < 3; ++c) {
            const float* p = ibase + (size_t)c * H * W + (size_t)r * W;
            ia[r][c] = *reinterpret_cast<const float4*>(p);
            ib[r][c] = *reinterpret_cast<const float4*>(p + 4);
        }

    // ---- stage targets tile into LDS as packed f16, even-parity layout ----
    const float* tbase = targets + (size_t)n * C * H * W;
    const bool interior = (h0 != 0) && (h0 != H - TH) && (w0 != 0) && (w0 != W - TW);
    {
        int rr = tid / SM_D;              // c*70 + r
        int d2 = tid - rr * SM_D;
        int r  = rr;                      // c=0 for tid<256
        int c  = 0;
        const int f2base = w0 / 2 - 2;    // float2 index of d2=0
        #pragma unroll
        for (int it = 0; it < 30; ++it) { // TOTAL 7560 = 29*256 + 136
            if (it < 29 || tid < 136) {
                const int gr = h0 + r - HALO;
                unsigned val;
                if (interior) {
                    const float2* rowp = reinterpret_cast<const float2*>(
                        tbase + ((size_t)c * H + gr) * W);
                    float2 v2 = rowp[f2base + d2];
                    h2 v; v[0] = (_Float16)v2.x; v[1] = (_Float16)v2.y;
                    val = __builtin_bit_cast(unsigned, v);
                } else {
                    const int gc = w0 - 4 + 2 * d2;
                    float f0 = 0.0f, f1 = 0.0f;
                    if ((unsigned)gr < (unsigned)H) {
                        const float* rowp = tbase + ((size_t)c * H + gr) * W;
                        if ((unsigned)gc       < (unsigned)W) f0 = rowp[gc];
                        if ((unsigned)(gc + 1) < (unsigned)W) f1 = rowp[gc + 1];
                    }
                    h2 v; v[0] = (_Float16)f0; v[1] = (_Float16)f1;
                    val = __builtin_bit_cast(unsigned, v);
                }
                sm_u[rr * SM_D + d2] = val;
            }
            rr += 7; r += 7; d2 += 4;                  // step 256 = 7*36 + 4
            if (d2 >= SM_D) { d2 -= SM_D; rr += 1; r += 1; }
            if (r >= SM_ROWS) { r -= SM_ROWS; c += 1; }
        }
    }

    // convert inputs while staging drains
    h2 ipk[2][3][4];
    #pragma unroll
    for (int r = 0; r < 2; ++r)
        #pragma unroll
        for (int c = 0; c < 3; ++c) {
            ipk[r][c][0][0] = (_Float16)ia[r][c].x; ipk[r][c][0][1] = (_Float16)ia[r][c].y;
            ipk[r][c][1][0] = (_Float16)ia[r][c].z; ipk[r][c][1][1] = (_Float16)ia[r][c].w;
            ipk[r][c][2][0] = (_Float16)ib[r][c].x; ipk[r][c][2][1] = (_Float16)ib[r][c].y;
            ipk[r][c][3][0] = (_Float16)ib[r][c].z; ipk[r][c][3][1] = (_Float16)ib[r][c].w;
        }
    __syncthreads();

    // ---- main loop over union target rows u=0..7 (LDS rows 2ty+u) ----
    // row u serves output A (=2ty) when u<=6 (di=u-3), output B when u>=1.
    h2 bE0[4], bO0[4], bE1[4], bO1[4];
    #pragma unroll
    for (int p = 0; p < 4; ++p) {
        bE0[p] = u2h(0x7bff7bffu); bO0[p] = u2h(0x7bff7bffu);
        bE1[p] = u2h(0x7bff7bffu); bO1[p] = u2h(0x7bff7bffu);
    }

    const unsigned* pa = &sm_u[(2 * ty) * SM_D + 4 * tx];
    unsigned t0[3][8], t1[3][8];
    load_rows(pa, t0);                       // row u=0

    #pragma unroll 1
    for (int u = 0; u < 8; u += 2) {
        load_rows(pa + SM_D, t1);            // row u+1 (prefetch before evals)
        {
            unsigned s0[3][7];
            align_row(t0, s0);
            eval_row(ipk[0], t0, s0, bE0, bO0);              // A: even u <= 6 always
            if (u > 0) eval_row(ipk[1], t0, s0, bE1, bO1);   // B: needs u >= 1
        }
        if (u < 6) load_rows(pa + 2 * SM_D, t0);             // row u+2 (prefetch)
        {
            unsigned s1[3][7];
            align_row(t1, s1);
            if (u < 6) eval_row(ipk[0], t1, s1, bE0, bO0);   // A: needs u+1 <= 6
            eval_row(ipk[1], t1, s1, bE1, bO1);              // B: u+1 >= 1 always
        }
        pa += 2 * SM_D;
    }

    float part = 0.0f;
    #pragma unroll
    for (int p = 0; p < 4; ++p) {
        h2 b0 = __builtin_elementwise_min(bE0[p], bO0[p]);
        h2 b1 = __builtin_elementwise_min(bE1[p], bO1[p]);
        part += (float)b0[0] + (float)b0[1] + (float)b1[0] + (float)b1[1];
    }

    // wave (64-lane) reduction, then cross-wave via LDS
    #pragma unroll
    for (int off = 32; off > 0; off >>= 1)
        part += __shfl_down(part, off, 64);

    __shared__ float wsum[BLK / 64];
    if ((tid & 63) == 0) wsum[tid >> 6] = part;
    __syncthreads();
    if (tid == 0) {
        float total = 0.0f;
        #pragma unroll
        for (int i = 0; i < BLK / 64; ++i) total += wsum[i];
        atomicAdd(out, total * (1.0f / (3.0f * (float)N * (float)H * (float)W)));
    }
}

extern "C" void kernel_launch(void* const* d_in, const int* in_sizes, int n_in,
                              void* d_out, int out_size, void* d_ws, size_t ws_size,
                              hipStream_t stream) {
    const float* inputs  = (const float*)d_in[0];
    const float* targets = (const float*)d_in[1];
    float* out = (float*)d_out;

    (void)hipMemsetAsync(out, 0, sizeof(float), stream);
    dim3 grid(W / TW, H / TH, N);
    local_l1_kernel<<<grid, BLK, 0, stream>>>(inputs, targets, out);
}

// Round 10
// 61.495 us; speedup vs baseline: 1.1777x; 1.1777x over previous
//
#include <hip/hip_runtime.h>

// LocalL1Loss: out = mean_{n,h,w} min_{7x7 shift} mean_c |in - shifted(tgt, zero-pad)|
// inputs/targets: (16, 3, 512, 512) fp32. Output: scalar fp32.
// R9: R7 structure (R4 tile/staging + pins) but eval loop in forced VOP3P asm.
// R5 was confounded (BLK=128 cost ~30us on its own); this is the clean
// scalarization test at BLK=256. s[3][7] precomputed once (R5 recomputed 84
// alignbits/di). Asm operands force VGPR materialization; WRITE_SIZE is the
// spill tripwire (R8: 31.7MB scratch = regression cause).

constexpr int N = 16, C = 3, H = 512, W = 512;
constexpr int K = 7, HALO = 3;
constexpr int TH = 32, TW = 64;          // output tile per block
constexpr int SM_ROWS = TH + 2 * HALO;   // 38
constexpr int SM_D = 36;                 // dwords/row: halves [w0-4 .. w0+67]
constexpr int BLK = 256;                 // 32 rows x 8 strips of 8 = 4 waves

typedef _Float16 h2 __attribute__((ext_vector_type(2)));

// Packed-f16 ops pinned to VOP3P.
#define PK_SUB(d, a, b) asm("v_pk_add_f16 %0, %1, %2 neg_lo:[0,1] neg_hi:[0,1]" \
                            : "=v"(d) : "v"(a), "v"(b))
#define PK_ABS(x)       asm("v_and_b32 %0, 0x7fff7fff, %0" : "+v"(x))
#define PK_ADD(d, a, b) asm("v_pk_add_f16 %0, %1, %2" : "=v"(d) : "v"(a), "v"(b))
#define PK_MIN(d, a)    asm("v_pk_min_f16 %0, %0, %1" : "+v"(d) : "v"(a))

__global__ __launch_bounds__(BLK, 4)
void local_l1_kernel(const float* __restrict__ inputs,
                     const float* __restrict__ targets,
                     float* __restrict__ out) {
    __shared__ unsigned sm_u[C * SM_ROWS * SM_D];   // 16,416 B

    const int tid = threadIdx.x;
    const int w0 = blockIdx.x * TW;
    const int h0 = blockIdx.y * TH;
    const int n  = blockIdx.z;

    // ---- issue input loads FIRST so they overlap the staging burst ----
    const int tx = tid & 7;    // strip index (w)
    const int ty = tid >> 3;   // row in tile (0..31)
    const float* ibase = inputs + ((size_t)n * C * H + (size_t)(h0 + ty)) * W
                       + (w0 + tx * 8);
    float4 ia[3], ib[3];
    #pragma unroll
    for (int c = 0; c < 3; ++c) {
        ia[c] = *reinterpret_cast<const float4*>(ibase + (size_t)c * H * W);
        ib[c] = *reinterpret_cast<const float4*>(ibase + (size_t)c * H * W + 4);
    }

    // ---- stage targets tile into LDS as packed f16, even-parity layout ----
    const float* tbase = targets + (size_t)n * C * H * W;
    const bool interior = (h0 != 0) && (h0 != H - TH) && (w0 != 0) && (w0 != W - TW);
    {
        int rr = tid / SM_D;              // 0..113 (c*38+r)
        int d2 = tid - rr * SM_D;
        int r  = rr;                      // c=0 for tid<256
        int c  = 0;
        const int f2base = w0 / 2 - 2;    // float2 index of d2=0
        #pragma unroll
        for (int it = 0; it < 17; ++it) {
            if (it < 16 || tid < 8) {     // TOTAL 4104 = 16*256 + 8
                const int gr = h0 + r - HALO;
                unsigned val;
                if (interior) {
                    const float2* rowp = reinterpret_cast<const float2*>(
                        tbase + ((size_t)c * H + gr) * W);
                    float2 v2 = rowp[f2base + d2];
                    h2 v; v[0] = (_Float16)v2.x; v[1] = (_Float16)v2.y;
                    val = __builtin_bit_cast(unsigned, v);
                } else {
                    const int gc = w0 - 4 + 2 * d2;
                    float f0 = 0.0f, f1 = 0.0f;
                    if ((unsigned)gr < (unsigned)H) {
                        const float* rowp = tbase + ((size_t)c * H + gr) * W;
                        if ((unsigned)gc       < (unsigned)W) f0 = rowp[gc];
                        if ((unsigned)(gc + 1) < (unsigned)W) f1 = rowp[gc + 1];
                    }
                    h2 v; v[0] = (_Float16)f0; v[1] = (_Float16)f1;
                    val = __builtin_bit_cast(unsigned, v);
                }
                sm_u[rr * SM_D + d2] = val;
            }
            rr += 7; r += 7; d2 += 4;                  // step 256 = 7*36 + 4
            if (d2 >= SM_D) { d2 -= SM_D; rr += 1; r += 1; }
            if (r >= SM_ROWS) { r -= SM_ROWS; c += 1; }
        }
    }

    // convert inputs to packed dwords while staging drains
    unsigned ipk[3][4];
    #pragma unroll
    for (int c = 0; c < 3; ++c) {
        h2 v0, v1, v2, v3;
        v0[0] = (_Float16)ia[c].x; v0[1] = (_Float16)ia[c].y;
        v1[0] = (_Float16)ia[c].z; v1[1] = (_Float16)ia[c].w;
        v2[0] = (_Float16)ib[c].x; v2[1] = (_Float16)ib[c].y;
        v3[0] = (_Float16)ib[c].z; v3[1] = (_Float16)ib[c].w;
        ipk[c][0] = __builtin_bit_cast(unsigned, v0);
        ipk[c][1] = __builtin_bit_cast(unsigned, v1);
        ipk[c][2] = __builtin_bit_cast(unsigned, v2);
        ipk[c][3] = __builtin_bit_cast(unsigned, v3);
    }
    __syncthreads();

    // ---- main loop: 8 outputs/thread, packed pairs, even/odd-dj split ----
    unsigned bestA[4], bestB[4];
    #pragma unroll
    for (int p = 0; p < 4; ++p) { bestA[p] = 0x7bff7bffu; bestB[p] = 0x7bff7bffu; }

    #pragma unroll
    for (int di = 0; di < K; ++di) {
        // dwords [tx*4 .. tx*4+7] of the 3 channel rows (b128 x2 each)
        unsigned t2[3][8];
        #pragma unroll
        for (int c = 0; c < 3; ++c) {
            const uint4* q = reinterpret_cast<const uint4*>(
                &sm_u[(c * SM_ROWS + (ty + di)) * SM_D + tx * 4]);
            uint4 lo = q[0], hi = q[1];
            t2[c][0] = lo.x; t2[c][1] = lo.y; t2[c][2] = lo.z; t2[c][3] = lo.w;
            t2[c][4] = hi.x; t2[c][5] = hi.y; t2[c][6] = hi.z; t2[c][7] = hi.w;
        }
        // odd-start pairs, computed once and pinned (asm uses force VGPRs)
        unsigned s[3][7];
        #pragma unroll
        for (int c = 0; c < 3; ++c)
            #pragma unroll
            for (int m = 0; m < 7; ++m)
                s[c][m] = __builtin_amdgcn_alignbit(t2[c][m + 1], t2[c][m], 16);

        // pair p covers halves starting at 8tx + 2p + dj + 1:
        //   dj odd  -> t2[p + (dj+1)/2];  dj even -> s[p + dj/2]
        #pragma unroll
        for (int dj = 0; dj < K; ++dj) {
            #pragma unroll
            for (int p = 0; p < 4; ++p) {
                unsigned q0, q1, q2;
                if (dj & 1) {
                    const int m = p + (dj + 1) / 2;
                    q0 = t2[0][m]; q1 = t2[1][m]; q2 = t2[2][m];
                } else {
                    const int m = p + dj / 2;
                    q0 = s[0][m]; q1 = s[1][m]; q2 = s[2][m];
                }
                unsigned x0, x1, x2, s01, dd;
                PK_SUB(x0, ipk[0][p], q0);
                PK_SUB(x1, ipk[1][p], q1);
                PK_SUB(x2, ipk[2][p], q2);
                PK_ABS(x0); PK_ABS(x1); PK_ABS(x2);
                PK_ADD(s01, x0, x1);
                PK_ADD(dd, s01, x2);
                if (dj & 1) PK_MIN(bestB[p], dd);
                else        PK_MIN(bestA[p], dd);
            }
        }
    }

    float part = 0.0f;
    #pragma unroll
    for (int p = 0; p < 4; ++p) {
        PK_MIN(bestA[p], bestB[p]);
        h2 b = __builtin_bit_cast(h2, bestA[p]);
        part += (float)b[0] + (float)b[1];
    }

    // wave (64-lane) reduction, then cross-wave via LDS
    #pragma unroll
    for (int off = 32; off > 0; off >>= 1)
        part += __shfl_down(part, off, 64);

    __shared__ float wsum[BLK / 64];
    if ((tid & 63) == 0) wsum[tid >> 6] = part;
    __syncthreads();
    if (tid == 0) {
        float total = 0.0f;
        #pragma unroll
        for (int i = 0; i < BLK / 64; ++i) total += wsum[i];
        atomicAdd(out, total * (1.0f / (3.0f * (float)N * (float)H * (float)W)));
    }
}

extern "C" void kernel_launch(void* const* d_in, const int* in_sizes, int n_in,
                              void* d_out, int out_size, void* d_ws, size_t ws_size,
                              hipStream_t stream) {
    const float* inputs  = (const float*)d_in[0];
    const float* targets = (const float*)d_in[1];
    float* out = (float*)d_out;

    (void)hipMemsetAsync(out, 0, sizeof(float), stream);
    dim3 grid(W / TW, H / TH, N);
    local_l1_kernel<<<grid, BLK, 0, stream>>>(inputs, targets, out);
}